// Round 1
// baseline (160.920 us; speedup 1.0000x reference)
//
#include <hip/hip_runtime.h>
#include <hip/hip_bf16.h>

typedef unsigned short u16;
typedef unsigned int u32;
typedef unsigned long long u64;
typedef __bf16 bf16x8 __attribute__((ext_vector_type(8)));
typedef float f32x16 __attribute__((ext_vector_type(16)));
typedef float f32x4 __attribute__((ext_vector_type(4)));

#define TEMP_INV (1.0f / 0.07f)
#define LOG2E 1.4426950408889634f

#if __has_builtin(__builtin_amdgcn_exp2f)
#define EXP2(x) __builtin_amdgcn_exp2f(x)
#else
#define EXP2(x) exp2f(x)
#endif

#define N_Z   524288    // 4096*128
#define N_POOL 131072   // 1024*128
#define TOT_CONV 2359296
#define CONV_BLKS 2304
#define MNB_BLKS 1024   // 256 rows * 16 segs / 4 wave-segs per block
#define ZERO_BLKS 9
#define P_CHUNKS 32
#define P_BYTES 3145728   // 32 chunks * 6 stats * 4096 * 4B
#define ZB_BYTES 32776    // RfK(16384) + RsK(16384) + accum(4) + ticket(4)
#define MNB_PAD 32784     // ZB_BYTES padded to 16B for mnbBits alignment

// ordered-key encode for atomic max on float (monotone u32 map)
__device__ __forceinline__ u32 fkey(float f) {
    u32 u = __float_as_uint(f);
    return (u & 0x80000000u) ? ~u : (u | 0x80000000u);
}
__device__ __forceinline__ float keyf(u32 k) {
    u32 u = (k & 0x80000000u) ? (k ^ 0x80000000u) : ~k;
    return __uint_as_float(u);
}

// global fragment load: row-major [.,128], lane li holds row, k = koff..koff+7
__device__ __forceinline__ bf16x8 ldfrag(const u16* __restrict__ base, int row, int koff) {
    return *(const bf16x8*)(base + (size_t)row * 128 + koff);
}

// LDS tile: 2 mats x 32 rows x 136-u16 stride (272 B = 17*16 B, odd 16B multiple -> b128 conflict-free)
#define TSTRIDE 136
#define TMAT 4352   // 32*136 u16 per mat

// ---------------- Kernel 0: f32->bf16 convert + mnb bit-pack + zero keys/accum/ticket ----------------
__global__ __launch_bounds__(256) void k_convert(
    const float* __restrict__ z, const float* __restrict__ spr,
    const float* __restrict__ f, const float* __restrict__ pag,
    const float* __restrict__ psp, const float* __restrict__ zmx,
    const float* __restrict__ mnb,
    u16* __restrict__ dst, u32* __restrict__ mnbBits) {
    int bid = blockIdx.x;
    if (bid >= CONV_BLKS + MNB_BLKS) {
        size_t byte = ((size_t)(bid - CONV_BLKS - MNB_BLKS) * 256 + threadIdx.x) * 16;
        if (byte < ZB_BYTES) {
            uint4 zero = {0, 0, 0, 0};
            *(uint4*)((char*)dst + (size_t)TOT_CONV * 2 + P_BYTES + byte) = zero;
        }
        return;
    }
    if (bid >= CONV_BLKS) {
        // pack mnb [256][4096] f32 (0/1) -> bits [256][128] u32; ballot gives 64 j per wave-op
        int gw = (bid - CONV_BLKS) * 4 + (threadIdx.x >> 6);   // 0..4095 wave-segs
        int l = threadIdx.x & 63;
        int row = gw >> 4;                 // 0..255
        int jseg = (gw & 15) << 8;         // 256-j segment
        const float* src = mnb + (size_t)row * 4096 + jseg + l;
        u64* db = (u64*)mnbBits + ((size_t)row << 6) + (jseg >> 6);
#pragma unroll
        for (int t = 0; t < 4; ++t) {
            u64 m = __ballot(src[t * 64] > 0.0f);   // bit l <-> j = jseg + t*64 + l
            if (l == t) db[t] = m;
        }
        return;
    }
    size_t e0 = ((size_t)bid * 256 + threadIdx.x) * 4;
    const float* src; size_t off;
    if (e0 < N_Z)                       { src = z;   off = e0; }
    else if (e0 < 2 * N_Z)              { src = spr; off = e0 - N_Z; }
    else if (e0 < 3 * N_Z)              { src = f;   off = e0 - 2 * N_Z; }
    else if (e0 < 3 * N_Z + N_POOL)     { src = pag; off = e0 - 3 * N_Z; }
    else if (e0 < 3 * N_Z + 2 * N_POOL) { src = psp; off = e0 - (3 * N_Z + N_POOL); }
    else                                { src = zmx; off = e0 - (3 * N_Z + 2 * N_POOL); }
    f32x4 v = *(const f32x4*)(src + off);
    ushort4 o;
    o.x = __bfloat16_as_ushort(__float2bfloat16(v[0]));
    o.y = __bfloat16_as_ushort(__float2bfloat16(v[1]));
    o.z = __bfloat16_as_ushort(__float2bfloat16(v[2]));
    o.w = __bfloat16_as_ushort(__float2bfloat16(v[3]));
    *(ushort4*)(dst + e0) = o;
}

// ---------------- Kernel 1: pool maxes ----------------
// grid (32, 32): 128 i rows per block (4 waves x 32), 32-pool-row chunk (1 tile, 1 barrier).
__global__ __launch_bounds__(256) void k_poolmax(
    const u16* __restrict__ f, const u16* __restrict__ spr,
    const u16* __restrict__ pag, const u16* __restrict__ psp,
    u32* __restrict__ RfK, u32* __restrict__ RsK) {
    __shared__ u16 stile[2 * TMAT];

    int tid = threadIdx.x;
    int lane = tid & 63, w = tid >> 6;
    int half = lane >> 5, li = lane & 31;
    int i = blockIdx.x * 128 + w * 32 + li;
    int pbase = blockIdx.y * 32;
    int srow = tid >> 4, sc16 = tid & 15;

    uint4 p00 = *(const uint4*)(pag + (size_t)(pbase + srow) * 128 + sc16 * 8);
    uint4 p01 = *(const uint4*)(pag + (size_t)(pbase + srow + 16) * 128 + sc16 * 8);
    uint4 p10 = *(const uint4*)(psp + (size_t)(pbase + srow) * 128 + sc16 * 8);
    uint4 p11 = *(const uint4*)(psp + (size_t)(pbase + srow + 16) * 128 + sc16 * 8);
    *(uint4*)(stile + (size_t)srow * TSTRIDE + sc16 * 8) = p00;
    *(uint4*)(stile + (size_t)(srow + 16) * TSTRIDE + sc16 * 8) = p01;
    *(uint4*)(stile + TMAT + (size_t)srow * TSTRIDE + sc16 * 8) = p10;
    *(uint4*)(stile + TMAT + (size_t)(srow + 16) * TSTRIDE + sc16 * 8) = p11;

    bf16x8 brf[8], brs[8];
#pragma unroll
    for (int kc = 0; kc < 8; ++kc) {
        int koff = kc * 16 + half * 8;
        brf[kc] = ldfrag(f, i, koff);
        brs[kc] = ldfrag(spr, i, koff);
    }
    __syncthreads();

    f32x16 accf = {}; f32x16 accs = {};
#pragma unroll
    for (int kc = 0; kc < 8; ++kc) {
        const u16* ab = stile + li * TSTRIDE + kc * 16 + half * 8;
        bf16x8 a0 = *(const bf16x8*)ab;
        bf16x8 a1 = *(const bf16x8*)(ab + TMAT);
        accf = __builtin_amdgcn_mfma_f32_32x32x16_bf16(a0, brf[kc], accf, 0, 0, 0);
        accs = __builtin_amdgcn_mfma_f32_32x32x16_bf16(a1, brs[kc], accs, 0, 0, 0);
    }
    float rmf = -1e30f, rms = -1e30f;
#pragma unroll
    for (int r = 0; r < 16; ++r) {
        rmf = fmaxf(rmf, accf[r]);
        rms = fmaxf(rms, accs[r]);
    }
    rmf = fmaxf(rmf, __shfl_xor(rmf, 32, 64));
    rms = fmaxf(rms, __shfl_xor(rms, 32, 64));
    if (half == 0) {
        atomicMax(RfK + i, fkey(rmf));
        atomicMax(RsK + i, fkey(rms));
    }
}

// ---------------- Kernel 2: main fused two-pass kernel ----------------
// grid (32, 32): 128 i per block (4 waves x 32), 128-j chunk (4 tiles of 32 per pass).
// Double-buffered LDS: ONE barrier per tile. Epilogue operands pre-staged:
// RfK/RsK decoded to LDS floats once per block; mnb consumed as preloaded bitmask.
__global__ __launch_bounds__(256) void k_main(
    const u16* __restrict__ zp, const u16* __restrict__ sp,
    const u16* __restrict__ fp, const u16* __restrict__ xp,
    const u32* __restrict__ mnbBits,
    const u32* __restrict__ RfK, const u32* __restrict__ RsK,
    float* __restrict__ P /* [32][6][4096] */) {
    __shared__ u16 stile[2][2 * TMAT];   // 2 x 17408 B
    __shared__ float sRf[128], sRs[128];

    int tid = threadIdx.x;
    int lane = tid & 63, w = tid >> 6;
    int half = lane >> 5, li = lane & 31;
    int i = blockIdx.x * 128 + w * 32 + li;
    int cbase = blockIdx.y * 128;
    int srow = tid >> 4, sc16 = tid & 15;

    // decode chunk's pool maxes into LDS once (broadcast reads later, conflict-free)
    if (tid < 128) sRf[tid] = keyf(RfK[cbase + tid]);
    else           sRs[tid - 128] = keyf(RsK[cbase + tid - 128]);

    bf16x8 bres0[8], bres1[8];
#pragma unroll
    for (int kc = 0; kc < 8; ++kc) {
        int koff = kc * 16 + half * 8;
        bres0[kc] = ldfrag(fp, i, koff);
        bres1[kc] = ldfrag(sp, i, koff);
    }

    float rfi = keyf(RfK[i]), rsi = keyf(RsK[i]);
    // one uint4 covers all 128 j of this block's chunk: word s <-> tile s
    uint4 mbts = *(const uint4*)(mnbBits + ((size_t)(i & 255) << 7) + (cbase >> 5));

    float wsum = 0.f, ones = 0.f, Az = 0.f, Ax = 0.f, Zz = 0.f, Zx = 0.f;
    const float c1 = TEMP_INV * LOG2E;
    u64 bitsv[4];

    uint4 pf[2][2];
    // prologue: tile0 -> buf0, prefetch tile1
    pf[0][0] = *(const uint4*)(fp + (size_t)(cbase + srow) * 128 + sc16 * 8);
    pf[0][1] = *(const uint4*)(fp + (size_t)(cbase + srow + 16) * 128 + sc16 * 8);
    pf[1][0] = *(const uint4*)(sp + (size_t)(cbase + srow) * 128 + sc16 * 8);
    pf[1][1] = *(const uint4*)(sp + (size_t)(cbase + srow + 16) * 128 + sc16 * 8);
    {
        u16* tb = stile[0];
        *(uint4*)(tb + (size_t)srow * TSTRIDE + sc16 * 8) = pf[0][0];
        *(uint4*)(tb + (size_t)(srow + 16) * TSTRIDE + sc16 * 8) = pf[0][1];
        *(uint4*)(tb + TMAT + (size_t)srow * TSTRIDE + sc16 * 8) = pf[1][0];
        *(uint4*)(tb + TMAT + (size_t)(srow + 16) * TSTRIDE + sc16 * 8) = pf[1][1];
    }
    {
        int j1 = cbase + 32;
        pf[0][0] = *(const uint4*)(fp + (size_t)(j1 + srow) * 128 + sc16 * 8);
        pf[0][1] = *(const uint4*)(fp + (size_t)(j1 + srow + 16) * 128 + sc16 * 8);
        pf[1][0] = *(const uint4*)(sp + (size_t)(j1 + srow) * 128 + sc16 * 8);
        pf[1][1] = *(const uint4*)(sp + (size_t)(j1 + srow + 16) * 128 + sc16 * 8);
    }

    // 8 tiles: s=0..3 pass0 (f,s_pr masks), s=4..7 pass1 (z,zmix stats)
#pragma unroll
    for (int s = 0; s < 8; ++s) {
        __syncthreads();   // buf[s&1] writes visible; buf[(s+1)&1] readers (iter s-1) done
        if (s < 7) {
            u16* tb = stile[(s + 1) & 1];
            *(uint4*)(tb + (size_t)srow * TSTRIDE + sc16 * 8) = pf[0][0];
            *(uint4*)(tb + (size_t)(srow + 16) * TSTRIDE + sc16 * 8) = pf[0][1];
            *(uint4*)(tb + TMAT + (size_t)srow * TSTRIDE + sc16 * 8) = pf[1][0];
            *(uint4*)(tb + TMAT + (size_t)(srow + 16) * TSTRIDE + sc16 * 8) = pf[1][1];
            if (s < 6) {
                int t = s + 2;
                const u16* m0 = (t < 4) ? fp : zp;
                const u16* m1 = (t < 4) ? sp : xp;
                int pj0 = cbase + (t & 3) * 32;
                pf[0][0] = *(const uint4*)(m0 + (size_t)(pj0 + srow) * 128 + sc16 * 8);
                pf[0][1] = *(const uint4*)(m0 + (size_t)(pj0 + srow + 16) * 128 + sc16 * 8);
                pf[1][0] = *(const uint4*)(m1 + (size_t)(pj0 + srow) * 128 + sc16 * 8);
                pf[1][1] = *(const uint4*)(m1 + (size_t)(pj0 + srow + 16) * 128 + sc16 * 8);
            }
        }
        if (s == 4) {   // swap residents to z,zmix (pass-0 MFMAs all consumed)
#pragma unroll
            for (int kc = 0; kc < 8; ++kc) {
                int koff = kc * 16 + half * 8;
                bres0[kc] = ldfrag(zp, i, koff);
                bres1[kc] = ldfrag(xp, i, koff);
            }
        }
        const u16* tb = stile[s & 1];
        f32x16 acc0 = {}; f32x16 acc1 = {};
#pragma unroll
        for (int kc = 0; kc < 8; ++kc) {
            const u16* ab = tb + li * TSTRIDE + kc * 16 + half * 8;
            bf16x8 a0 = *(const bf16x8*)ab;
            bf16x8 a1 = *(const bf16x8*)(ab + TMAT);
            acc0 = __builtin_amdgcn_mfma_f32_32x32x16_bf16(a0, bres0[kc], acc0, 0, 0, 0);
            acc1 = __builtin_amdgcn_mfma_f32_32x32x16_bf16(a1, bres1[kc], acc1, 0, 0, 0);
        }
        // elem r: j = j0 + (r&3) + 8*(r>>2) + 4*half  (m74/m101 C/D layout), col i = lane&31
        if (s < 4) {
            int j0 = cbase + s * 32;
            u32 mb = (s == 0) ? mbts.x : (s == 1) ? mbts.y : (s == 2) ? mbts.z : mbts.w;
            u64 bits = 0;
#pragma unroll
            for (int q = 0; q < 4; ++q) {
                int jb = j0 + q * 8 + half * 4;
                f32x4 rf4 = *(const f32x4*)(sRf + (jb - cbase));
                f32x4 rs4 = *(const f32x4*)(sRs + (jb - cbase));
#pragma unroll
                for (int t = 0; t < 4; ++t) {
                    int r = q * 4 + t;
                    int j = jb + t;
                    bool nm = (j != i);
                    bool mob = acc0[r] > fminf(rfi, rf4[t]);
                    bool meb = acc1[r] > fminf(rsi, rs4[t]);
                    bool mnbv = (mb >> (q * 8 + half * 4 + t)) & 1u;   // bit j-j0
                    u32 e = ((mob && nm) ? 1u : 0u) | ((meb && nm) ? 2u : 0u) |
                            (((mob || mnbv) && nm) ? 4u : 0u);
                    bits |= (u64)e << (4 * r);
                }
            }
            bitsv[s] = bits;
        } else {
            u64 bits = bitsv[s - 4];
#pragma unroll
            for (int r = 0; r < 16; ++r) {
                u32 e = (u32)(bits >> (4 * r)) & 7u;
                float w1 = (e & 1u) ? 1.0f : 0.0f;
                float wv = w1 + ((e & 2u) ? 0.5f : 0.0f);
                float ng = (e & 4u) ? 1.0f : 0.0f;
                float lvz = acc0[r], lvx = acc1[r];
                wsum += wv; ones += w1;
                Az = fmaf(wv, lvz, Az);
                Ax = fmaf(wv, lvx, Ax);
                Zz = fmaf(ng, EXP2(fmaf(lvz, c1, -c1)), Zz);
                Zx = fmaf(ng, EXP2(fmaf(lvx, c1, -c1)), Zx);
            }
        }
    }

    // combine two lane-halves (disjoint j sets, same i); coalesced SoA partial store
    wsum += __shfl_xor(wsum, 32, 64);
    ones += __shfl_xor(ones, 32, 64);
    Az += __shfl_xor(Az, 32, 64);
    Ax += __shfl_xor(Ax, 32, 64);
    Zz += __shfl_xor(Zz, 32, 64);
    Zx += __shfl_xor(Zx, 32, 64);
    if (half == 0) {
        float* pb = P + ((size_t)blockIdx.y * 6) * 4096 + i;
        pb[0] = wsum;
        pb[4096] = ones;
        pb[2 * 4096] = Az;
        pb[3 * 4096] = Ax;
        pb[4 * 4096] = Zz;
        pb[5 * 4096] = Zx;
    }
}

// ---------------- Kernel 3: reduce 32 chunks, per-m block means, ticketed final sum ----------------
__global__ __launch_bounds__(256) void k_final(const float* __restrict__ P,
                                               float* __restrict__ accum, u32* __restrict__ ticket,
                                               u32* __restrict__ out) {
    int t = threadIdx.x;
    int i = blockIdx.x * 256 + t;
    float wsum = 0.f, ones = 0.f, Az = 0.f, Ax = 0.f, Zz = 0.f, Zx = 0.f;
#pragma unroll
    for (int c = 0; c < P_CHUNKS; ++c) {
        const float* pb = P + ((size_t)c * 6) * 4096 + i;
        wsum += pb[0];
        ones += pb[4096];
        Az += pb[2 * 4096];
        Ax += pb[3 * 4096];
        Zz += pb[4 * 4096];
        Zx += pb[5 * 4096];
    }
    float dw = wsum > 0.f ? wsum : 1.0f;
    float lz = Zz > 0.f ? logf(Zz) : 0.f;
    float lx = Zx > 0.f ? logf(Zx) : 0.f;
    float mlz = (TEMP_INV * Az - wsum * (TEMP_INV + lz)) / dw;
    float mlx = (TEMP_INV * Ax - wsum * (TEMP_INV + lx)) / dw;
    float si = ones > 0.f ? wsum : 0.f;
    float ci = (mlz + mlx) * si;
#pragma unroll
    for (int d = 1; d < 64; d <<= 1) {
        ci += __shfl_xor(ci, d, 64);
        si += __shfl_xor(si, d, 64);
    }
    __shared__ float rc[4], rs[4];
    int wv = t >> 6;
    if ((t & 63) == 0) { rc[wv] = ci; rs[wv] = si; }
    __syncthreads();
    if (t == 0) {
        float cs = rc[0] + rc[1] + rc[2] + rc[3];
        float ss = rs[0] + rs[1] + rs[2] + rs[3];
        float ratio = ss > 0.f ? cs / ss : 0.f;
        atomicAdd(accum, ratio);
        __threadfence();
        u32 old = atomicAdd(ticket, 1u);
        if (old == 15u) {
            float total = atomicAdd(accum, 0.0f);  // all 16 adds complete
            __hip_bfloat16 hb = __float2bfloat16(-total / 32.0f);
            u32 bits = (u32)__bfloat16_as_ushort(hb);
            out[0] = (bits << 16) | bits;  // bf16/f32 dual-interpretation hedge
        }
    }
}

extern "C" void kernel_launch(void* const* d_in, const int* in_sizes, int n_in,
                              void* d_out, int out_size, void* d_ws, size_t ws_size,
                              hipStream_t stream) {
    const float* z   = (const float*)d_in[0];
    const float* spr = (const float*)d_in[1];
    const float* f   = (const float*)d_in[2];
    const float* pag = (const float*)d_in[3];
    const float* psp = (const float*)d_in[4];
    const float* zmx = (const float*)d_in[5];
    const float* mnb = (const float*)d_in[6];

    // ws: bf16 features [TOT_CONV u16] | P[32][6][4096] f32 | RfK[4096] | RsK[4096]
    //     | accum | ticket | pad8 | mnbBits[256][128] u32   (total ~8.03 MB)
    u16* cb = (u16*)d_ws;
    u16* zb   = cb;
    u16* sprb = cb + N_Z;
    u16* fb   = cb + 2 * N_Z;
    u16* pagb = cb + 3 * N_Z;
    u16* pspb = cb + 3 * N_Z + N_POOL;
    u16* zmxb = cb + 3 * N_Z + 2 * N_POOL;
    float* P     = (float*)(cb + TOT_CONV);
    u32* RfK     = (u32*)((char*)P + P_BYTES);
    u32* RsK     = RfK + 4096;
    float* accum = (float*)(RsK + 4096);
    u32* ticket  = (u32*)(accum + 1);
    u32* mnbBits = (u32*)((char*)P + P_BYTES + MNB_PAD);

    k_convert<<<CONV_BLKS + MNB_BLKS + ZERO_BLKS, 256, 0, stream>>>(z, spr, f, pag, psp, zmx, mnb, cb, mnbBits);
    k_poolmax<<<dim3(32, 32), 256, 0, stream>>>(fb, sprb, pagb, pspb, RfK, RsK);
    k_main<<<dim3(32, 32), 256, 0, stream>>>(zb, sprb, fb, zmxb, mnbBits, RfK, RsK, P);
    k_final<<<16, 256, 0, stream>>>(P, accum, ticket, (u32*)d_out);
}